// Round 3
// baseline (124.421 us; speedup 1.0000x reference)
//
#include <hip/hip_runtime.h>
#include <hip/hip_bf16.h>

typedef unsigned short u16;
typedef unsigned int u32;
typedef __bf16 bf16x8 __attribute__((ext_vector_type(8)));
typedef float floatx4 __attribute__((ext_vector_type(4)));

#define MFMA16(a,b,c) __builtin_amdgcn_mfma_f32_16x16x32_bf16((a),(b),(c),0,0,0)
#define AS1 __attribute__((address_space(1)))
#define AS3 __attribute__((address_space(3)))
#define VMCNT0 asm volatile("s_waitcnt vmcnt(0)" ::: "memory")

__device__ __forceinline__ void gl16(const void* g, void* l){
  __builtin_amdgcn_global_load_lds((const AS1 void*)g, (AS3 void*)l, 16, 0, 0);
}

__device__ __forceinline__ u16 f2bf(float f){
  u32 u = __builtin_bit_cast(u32, f);
  u += 0x7FFFu + ((u >> 16) & 1u);
  return (u16)(u >> 16);
}
__device__ __forceinline__ float bf2f(u16 h){
  u32 u = ((u32)h) << 16;
  return __builtin_bit_cast(float, u);
}
__device__ __forceinline__ bf16x8 ldfrag(const u16* p){
  return *(const bf16x8*)p;
}

// ---------------- K0: combine weights + zero sum buffers ----
__global__ __launch_bounds__(256) void k0_prep(
    const float* __restrict__ W0, const float* __restrict__ b0,
    const float* __restrict__ W1, const float* __restrict__ b1,
    const float* __restrict__ Wc0, const float* __restrict__ bc0,
    const float* __restrict__ Wc1, const float* __restrict__ bc1,
    u16* __restrict__ WgT, u16* __restrict__ WcT,
    float* __restrict__ bias_g, float* __restrict__ bias_c,
    float* __restrict__ sums /*colsum|rowsum, 32768 f32*/){
  int id = blockIdx.x*256 + threadIdx.x;
  if (id < 32768) sums[id] = 0.0f;
  if (id < 128*384) {
    int n = id / 384, k = id % 384;
    float v;
    if (k < 128)       v = W0[(k*3+0)*128 + n] + W1[(k*3+0)*128 + n];
    else if (k < 256){ int f = k-128; v = W0[(f*3+1)*128+n] + W0[(f*3+2)*128+n]; }
    else             { int f = k-256; v = W1[(f*3+1)*128+n] + W1[(f*3+2)*128+n]; }
    WgT[(size_t)n*384 + k] = f2bf(v);
  } else {
    int id2 = id - 128*384;  // < 64*384
    int n = id2 / 384, k = id2 % 384;
    float v;
    if (k < 128)       v = Wc0[(k*3+0)*64 + n] + Wc1[(k*3+0)*64 + n];
    else if (k < 256){ int f = k-128; v = Wc0[(f*3+1)*64+n] + Wc0[(f*3+2)*64+n]; }
    else             { int f = k-256; v = Wc1[(f*3+1)*64+n] + Wc1[(f*3+2)*64+n]; }
    WcT[(size_t)n*384 + k] = f2bf(v);
  }
  if (blockIdx.x == 0) {
    if (threadIdx.x < 128) bias_g[threadIdx.x] = b0[threadIdx.x] + b1[threadIdx.x];
    if (threadIdx.x < 64)  bias_c[threadIdx.x] = bc0[threadIdx.x] + bc1[threadIdx.x];
  }
}

// ---------------- K1: adj pass: row/col sums + bf16 copy + transposed bf16 copy
__global__ __launch_bounds__(256) void k1_adj(const float* __restrict__ adj,
    u16* __restrict__ adjbf, u16* __restrict__ adjTbf,
    float* __restrict__ colsum, float* __restrict__ rowsum){
  __shared__ u16 lt[64][72];            // lt[j_local][i_local]
  int b = blockIdx.z;
  int i0 = blockIdx.y << 6, j0 = blockIdx.x << 6;
  int t = threadIdx.x;
  int r = t >> 2, cq = t & 3;
  size_t base = ((size_t)b << 20);
  const float4* s4 = (const float4*)(adj + base + (size_t)(i0 + r)*1024 + j0 + (cq<<4));
  float v[16];
  #pragma unroll
  for (int q = 0; q < 4; q++) {
    float4 f = s4[q];
    v[4*q]=f.x; v[4*q+1]=f.y; v[4*q+2]=f.z; v[4*q+3]=f.w;
  }
  u32 u8[8];
  #pragma unroll
  for (int q = 0; q < 8; q++)
    u8[q] = (u32)f2bf(v[2*q]) | ((u32)f2bf(v[2*q+1]) << 16);
  uint4* d = (uint4*)(adjbf + base + (size_t)(i0 + r)*1024 + j0 + (cq<<4));
  d[0] = make_uint4(u8[0],u8[1],u8[2],u8[3]);
  d[1] = make_uint4(u8[4],u8[5],u8[6],u8[7]);
  float rs = 0.f;
  #pragma unroll
  for (int q = 0; q < 16; q++) rs += v[q];
  rs += __shfl_down(rs, 1, 64);
  rs += __shfl_down(rs, 2, 64);
  if (cq == 0) atomicAdd(&rowsum[b*1024 + i0 + r], rs);
  #pragma unroll
  for (int q = 0; q < 16; q++)
    lt[(cq<<4) + q][r] = (u16)(u8[q>>1] >> ((q&1)*16));
  __syncthreads();
  uint4 q0 = *(const uint4*)&lt[r][(cq<<4)];
  uint4 q1 = *(const uint4*)&lt[r][(cq<<4) + 8];
  uint4* dT = (uint4*)(adjTbf + base + (size_t)(j0 + r)*1024 + i0 + (cq<<4));
  dT[0] = q0; dT[1] = q1;
  u32 w8[8] = {q0.x,q0.y,q0.z,q0.w,q1.x,q1.y,q1.z,q1.w};
  float cs = 0.f;
  #pragma unroll
  for (int q = 0; q < 8; q++)
    cs += bf2f((u16)(w8[q] & 0xFFFFu)) + bf2f((u16)(w8[q] >> 16));
  cs += __shfl_down(cs, 1, 64);
  cs += __shfl_down(cs, 2, 64);
  if (cq == 0) atomicAdd(&colsum[b*1024 + j0 + r], cs);
}

// ---------------- K1c: finalize dinv in place ----
__global__ __launch_bounds__(256) void k1c_dinv(float* __restrict__ colsum,
                                                float* __restrict__ rowsum){
  int i = blockIdx.x*256 + threadIdx.x;   // 16384
  colsum[i] = 1.0f / (colsum[i] + 1.0f);  // becomes d0inv
  rowsum[i] = 1.0f / (rowsum[i] + 1.0f);  // becomes d1inv
}

// ---------------- K1b: stage X: XC/XC2 rows (coalesced) + Xt feature-major via LDS transpose
__global__ __launch_bounds__(256) void k1b_x(const float* __restrict__ inp,
    const float* __restrict__ hx, u16* __restrict__ XC,
    u16* __restrict__ Xt, u16* __restrict__ XC2){
  __shared__ u16 XT[128][80];           // [feat][node_local], stride 160B = odd*16B
  int t = threadIdx.x;
  int r = t >> 2;                       // node local 0..63
  int row = blockIdx.x*64 + r;
  int fq = t & 3;
  const float4* ip = (const float4*)(inp + (size_t)row*64 + fq*16);
  const float4* hp = (const float4*)(hx  + (size_t)row*64 + fq*16);
  float iv[16], hv[16];
  #pragma unroll
  for (int q=0;q<4;q++){
    float4 a = ip[q]; iv[4*q]=a.x; iv[4*q+1]=a.y; iv[4*q+2]=a.z; iv[4*q+3]=a.w;
    float4 c = hp[q]; hv[4*q]=c.x; hv[4*q+1]=c.y; hv[4*q+2]=c.z; hv[4*q+3]=c.w;
  }
  u16 ib[16], hb[16];
  #pragma unroll
  for (int q=0;q<16;q++){ ib[q]=f2bf(iv[q]); hb[q]=f2bf(hv[q]); }
  u32 pi[8], ph[8];
  #pragma unroll
  for (int q=0;q<8;q++){
    pi[q] = (u32)ib[2*q] | ((u32)ib[2*q+1]<<16);
    ph[q] = (u32)hb[2*q] | ((u32)hb[2*q+1]<<16);
  }
  size_t rbase = (size_t)row*384;
  *(uint4*)(XC + rbase + fq*16)          = make_uint4(pi[0],pi[1],pi[2],pi[3]);
  *(uint4*)(XC + rbase + fq*16 + 8)      = make_uint4(pi[4],pi[5],pi[6],pi[7]);
  *(uint4*)(XC + rbase + 64 + fq*16)     = make_uint4(ph[0],ph[1],ph[2],ph[3]);
  *(uint4*)(XC + rbase + 64 + fq*16 + 8) = make_uint4(ph[4],ph[5],ph[6],ph[7]);
  *(uint4*)(XC2 + rbase + fq*16)         = make_uint4(pi[0],pi[1],pi[2],pi[3]);
  *(uint4*)(XC2 + rbase + fq*16 + 8)     = make_uint4(pi[4],pi[5],pi[6],pi[7]);
  #pragma unroll
  for (int q=0;q<16;q++){
    XT[fq*16+q][r]      = ib[q];
    XT[64+fq*16+q][r]   = hb[q];
  }
  __syncthreads();
  // coalesced write-out: thread -> feat t>>1, half t&1 (32 nodes = 64B)
  int feat = t >> 1, half = t & 1;
  int b = blockIdx.x >> 4, n0 = (blockIdx.x & 15)*64;
  const uint4* src = (const uint4*)&XT[feat][half*32];
  uint4* dst = (uint4*)(Xt + (size_t)b*131072 + (size_t)feat*1024 + n0 + half*32);
  dst[0]=src[0]; dst[1]=src[1]; dst[2]=src[2]; dst[3]=src[3];
}

// ---------------- K2: Y = dinv * ((adj(+T) @ X) + X) ; 2-phase dbuf MFMA GEMM
__global__ __launch_bounds__(256) void k2_y(const u16* __restrict__ adjbf,
    const u16* __restrict__ adjTbf, const u16* __restrict__ Xt,
    const float* __restrict__ inp, const float* __restrict__ hx,
    const float* __restrict__ d0inv, const float* __restrict__ d1inv,
    u16* __restrict__ XC, u16* __restrict__ XC2){
  __shared__ u16 Al[2][64*32];    // 8KB
  __shared__ u16 Bl[2][128*32];   // 16KB
  int bid0 = blockIdx.x;
  int bid = (bid0 & 7)*64 + (bid0 >> 3);      // XCD chunked swizzle (512 = 8*64)
  int mt = bid & 15, b = (bid>>4)&15, T = bid>>8;
  const u16* A = (T ? adjTbf : adjbf) + ((size_t)b<<20) + (size_t)mt*64*1024;
  const float* dinv = (T ? d1inv : d0inv) + b*1024;
  const u16* Xb = Xt + (size_t)b*131072;
  int t = threadIdx.x, w = t>>6, l = t&63, lr = l&15, lg = l>>4;
  int wr = w>>1, wc = w&1;
  const char* Ag  = (const char*)A  + (size_t)(w*16 + (l>>2))*2048 + (l&3)*16;
  const char* Bg0 = (const char*)Xb + (size_t)((w*2  )*16 + (l>>2))*2048 + (l&3)*16;
  const char* Bg1 = (const char*)Xb + (size_t)((w*2+1)*16 + (l>>2))*2048 + (l&3)*16;
  floatx4 acc[2][4] = {};
  // prologue stage
  gl16(Ag,  (char*)Al[0] + w*1024);
  gl16(Bg0, (char*)Bl[0] + (w*2  )*1024);
  gl16(Bg1, (char*)Bl[0] + (w*2+1)*1024);
  VMCNT0; __syncthreads();
  int cur = 0;
  for (int kk = 32; kk < 1024; kk += 32){
    gl16(Ag  + kk*2, (char*)Al[cur^1] + w*1024);
    gl16(Bg0 + kk*2, (char*)Bl[cur^1] + (w*2  )*1024);
    gl16(Bg1 + kk*2, (char*)Bl[cur^1] + (w*2+1)*1024);
    bf16x8 af[2], bfr[4];
    #pragma unroll
    for (int mi = 0; mi < 2; mi++)
      af[mi] = *(const bf16x8*)((const char*)Al[cur] + (size_t)(wr*32+mi*16+lr)*64 + lg*16);
    #pragma unroll
    for (int nf = 0; nf < 4; nf++)
      bfr[nf] = *(const bf16x8*)((const char*)Bl[cur] + (size_t)(wc*64+nf*16+lr)*64 + lg*16);
    #pragma unroll
    for (int mi = 0; mi < 2; mi++)
      #pragma unroll
      for (int nf = 0; nf < 4; nf++)
        acc[mi][nf] = MFMA16(af[mi], bfr[nf], acc[mi][nf]);
    VMCNT0; __syncthreads();
    cur ^= 1;
  }
  {
    bf16x8 af[2], bfr[4];
    #pragma unroll
    for (int mi = 0; mi < 2; mi++)
      af[mi] = *(const bf16x8*)((const char*)Al[cur] + (size_t)(wr*32+mi*16+lr)*64 + lg*16);
    #pragma unroll
    for (int nf = 0; nf < 4; nf++)
      bfr[nf] = *(const bf16x8*)((const char*)Bl[cur] + (size_t)(wc*64+nf*16+lr)*64 + lg*16);
    #pragma unroll
    for (int mi = 0; mi < 2; mi++)
      #pragma unroll
      for (int nf = 0; nf < 4; nf++)
        acc[mi][nf] = MFMA16(af[mi], bfr[nf], acc[mi][nf]);
  }
  int outcol = T ? 256 : 128;
  #pragma unroll
  for (int mi = 0; mi < 2; mi++) {
    #pragma unroll
    for (int nf = 0; nf < 4; nf++) {
      #pragma unroll
      for (int rr = 0; rr < 4; rr++) {
        int row = mt*64 + wr*32 + mi*16 + lg*4 + rr;
        int col = wc*64 + nf*16 + lr;
        float xv = (col < 64) ? inp[(size_t)(b*1024+row)*64 + col]
                              : hx [(size_t)(b*1024+row)*64 + (col-64)];
        float v2 = (acc[mi][nf][rr] + xv) * dinv[row];
        u16 bv = f2bf(v2);
        size_t grow = (size_t)(b*1024 + row)*384;
        XC[grow + outcol + col] = bv;
        if (col < 64) XC2[grow + outcol + col] = bv;
      }
    }
  }
}

// ---------------- K3: gates GEMM + sigmoid; emit u, S row-major + St via LDS transpose
__global__ __launch_bounds__(256) void k3_gates(const u16* __restrict__ XC,
    const u16* __restrict__ WgT, const float* __restrict__ bias_g,
    const float* __restrict__ hx, u16* __restrict__ XC2,
    u16* __restrict__ St, float* __restrict__ uBuf){
  __shared__ u16 SL[64][80];          // [col][row_local]
  int t = threadIdx.x, w = t >> 6, l = t & 63, lr = l & 15, lg = l >> 4;
  int r0 = blockIdx.x*64 + w*16;
  floatx4 acc[8] = {};
  for (int kk = 0; kk < 384; kk += 32) {
    int ko = kk + lg*8;
    bf16x8 a = ldfrag(XC + (size_t)(r0 + lr)*384 + ko);
    #pragma unroll
    for (int nf = 0; nf < 8; nf++)
      acc[nf] = MFMA16(a, ldfrag(WgT + (size_t)(nf*16+lr)*384 + ko), acc[nf]);
  }
  #pragma unroll
  for (int nf = 0; nf < 8; nf++) {
    #pragma unroll
    for (int rr = 0; rr < 4; rr++) {
      int row = r0 + lg*4 + rr;
      int col = nf*16 + lr;
      float pre = acc[nf][rr] + bias_g[col];
      float s = 1.0f / (1.0f + __expf(-pre));
      if (col < 64) {            // r gate
        float sh = s * hx[(size_t)row*64 + col];
        u16 bv = f2bf(sh);
        XC2[(size_t)row*384 + 64 + col] = bv;
        SL[col][w*16 + lg*4 + rr] = bv;
      } else {                   // u gate
        uBuf[(size_t)row*64 + (col-64)] = s;
      }
    }
  }
  __syncthreads();
  // coalesced St write: thread -> col t>>2, quarter t&3 (16 nodes = 32B)
  int col = t >> 2, q = t & 3;
  int gb = blockIdx.x >> 4, n0 = (blockIdx.x & 15)*64;
  const uint4* src = (const uint4*)&SL[col][q*16];
  uint4* dst = (uint4*)(St + (size_t)gb*65536 + (size_t)col*1024 + n0 + q*16);
  dst[0]=src[0]; dst[1]=src[1];
}

// ---------------- K4: Z = dinv * ((adj(+T) @ S) + S) ; 2-phase dbuf MFMA GEMM
__global__ __launch_bounds__(256) void k4_z(const u16* __restrict__ adjbf,
    const u16* __restrict__ adjTbf, const u16* __restrict__ St,
    const float* __restrict__ d0inv, const float* __restrict__ d1inv,
    u16* __restrict__ XC2){
  __shared__ u16 Al[2][64*32];    // 8KB
  __shared__ u16 Bl[2][64*32];    // 8KB
  int bid0 = blockIdx.x;
  int bid = (bid0 & 7)*64 + (bid0 >> 3);
  int mt = bid & 15, b = (bid>>4)&15, T = bid>>8;
  const u16* A = (T ? adjTbf : adjbf) + ((size_t)b<<20) + (size_t)mt*64*1024;
  const float* dinv = (T ? d1inv : d0inv) + b*1024;
  const u16* Sb = St + (size_t)b*65536;
  int t = threadIdx.x, w = t>>6, l = t&63, lr = l&15, lg = l>>4;
  int wr = w>>1, wc = w&1;
  const char* Ag = (const char*)A  + (size_t)(w*16 + (l>>2))*2048 + (l&3)*16;
  const char* Bg = (const char*)Sb + (size_t)(w*16 + (l>>2))*2048 + (l&3)*16;
  floatx4 acc[2][2] = {};
  gl16(Ag, (char*)Al[0] + w*1024);
  gl16(Bg, (char*)Bl[0] + w*1024);
  VMCNT0; __syncthreads();
  int cur = 0;
  for (int kk = 32; kk < 1024; kk += 32){
    gl16(Ag + kk*2, (char*)Al[cur^1] + w*1024);
    gl16(Bg + kk*2, (char*)Bl[cur^1] + w*1024);
    bf16x8 af[2], bfr[2];
    #pragma unroll
    for (int mi = 0; mi < 2; mi++)
      af[mi] = *(const bf16x8*)((const char*)Al[cur] + (size_t)(wr*32+mi*16+lr)*64 + lg*16);
    #pragma unroll
    for (int nf = 0; nf < 2; nf++)
      bfr[nf] = *(const bf16x8*)((const char*)Bl[cur] + (size_t)(wc*32+nf*16+lr)*64 + lg*16);
    #pragma unroll
    for (int mi = 0; mi < 2; mi++)
      #pragma unroll
      for (int nf = 0; nf < 2; nf++)
        acc[mi][nf] = MFMA16(af[mi], bfr[nf], acc[mi][nf]);
    VMCNT0; __syncthreads();
    cur ^= 1;
  }
  {
    bf16x8 af[2], bfr[2];
    #pragma unroll
    for (int mi = 0; mi < 2; mi++)
      af[mi] = *(const bf16x8*)((const char*)Al[cur] + (size_t)(wr*32+mi*16+lr)*64 + lg*16);
    #pragma unroll
    for (int nf = 0; nf < 2; nf++)
      bfr[nf] = *(const bf16x8*)((const char*)Bl[cur] + (size_t)(wc*32+nf*16+lr)*64 + lg*16);
    #pragma unroll
    for (int mi = 0; mi < 2; mi++)
      #pragma unroll
      for (int nf = 0; nf < 2; nf++)
        acc[mi][nf] = MFMA16(af[mi], bfr[nf], acc[mi][nf]);
  }
  int zcol = T ? 320 : 192;
  #pragma unroll
  for (int mi = 0; mi < 2; mi++) {
    #pragma unroll
    for (int nf = 0; nf < 2; nf++) {
      #pragma unroll
      for (int rr = 0; rr < 4; rr++) {
        int row = mt*64 + wr*32 + mi*16 + lg*4 + rr;
        int col = wc*32 + nf*16 + lr;
        size_t grow = (size_t)(b*1024 + row)*384;
        float sval = bf2f(XC2[grow + 64 + col]);
        float v2 = (acc[mi][nf][rr] + sval) * dinv[row];
        XC2[grow + zcol + col] = f2bf(v2);
      }
    }
  }
}

// ---------------- K5: candidate GEMM + tanh + GRU update -> out
__global__ __launch_bounds__(256) void k5_out(const u16* __restrict__ XC2,
    const u16* __restrict__ WcT, const float* __restrict__ bias_c,
    const float* __restrict__ uBuf, const float* __restrict__ hx,
    float* __restrict__ out){
  int w = threadIdx.x >> 6, l = threadIdx.x & 63, lr = l & 15, lg = l >> 4;
  int r0 = blockIdx.x*64 + w*16;
  floatx4 acc[4] = {};
  for (int kk = 0; kk < 384; kk += 32) {
    int ko = kk + lg*8;
    bf16x8 a = ldfrag(XC2 + (size_t)(r0 + lr)*384 + ko);
    #pragma unroll
    for (int nf = 0; nf < 4; nf++)
      acc[nf] = MFMA16(a, ldfrag(WcT + (size_t)(nf*16+lr)*384 + ko), acc[nf]);
  }
  #pragma unroll
  for (int nf = 0; nf < 4; nf++) {
    #pragma unroll
    for (int rr = 0; rr < 4; rr++) {
      int row = r0 + lg*4 + rr;
      int col = nf*16 + lr;
      float pre = acc[nf][rr] + bias_c[col];
      pre = fminf(fmaxf(pre, -15.f), 15.f);
      float e2 = __expf(2.0f*pre);
      float c = (e2 - 1.0f) / (e2 + 1.0f);
      float u = uBuf[(size_t)row*64 + col];
      float h = hx[(size_t)row*64 + col];
      out[(size_t)row*64 + col] = u*h + (1.0f - u)*c;
    }
  }
}

extern "C" void kernel_launch(void* const* d_in, const int* in_sizes, int n_in,
                              void* d_out, int out_size, void* d_ws, size_t ws_size,
                              hipStream_t stream) {
  (void)in_sizes; (void)n_in; (void)out_size; (void)ws_size;
  const float* inp = (const float*)d_in[0];
  const float* hx  = (const float*)d_in[1];
  const float* adj = (const float*)d_in[2];
  const float* W0  = (const float*)d_in[3];
  const float* b0  = (const float*)d_in[4];
  const float* W1  = (const float*)d_in[5];
  const float* b1  = (const float*)d_in[6];
  const float* Wc0 = (const float*)d_in[7];
  const float* bc0 = (const float*)d_in[8];
  const float* Wc1 = (const float*)d_in[9];
  const float* bc1 = (const float*)d_in[10];
  float* out = (float*)d_out;
  char* ws = (char*)d_ws;

  float* colsum = (float*)(ws + 0);            // -> d0inv after k1c
  float* rowsum = (float*)(ws + 65536);        // -> d1inv after k1c
  u16* adjbf  = (u16*)(ws + 131072);           // 33554432 B
  u16* adjTbf = (u16*)(ws + 33685504);         // 33554432 B
  u16* Xt     = (u16*)(ws + 67239936);         // 4194304 B
  u16* XC     = (u16*)(ws + 71434240);         // 12582912 B
  u16* XC2    = (u16*)(ws + 84017152);         // 12582912 B
  u16* St     = (u16*)(ws + 96600064);         // 2097152 B
  float* uBuf = (float*)(ws + 98697216);       // 4194304 B
  u16* WgT    = (u16*)(ws + 102891520);        // 98304 B
  u16* WcT    = (u16*)(ws + 102989824);        // 49152 B
  float* bias_g = (float*)(ws + 103038976);    // 512 B
  float* bias_c = (float*)(ws + 103039488);    // 256 B

  hipLaunchKernelGGL(k0_prep, dim3(288), dim3(256), 0, stream,
                     W0, b0, W1, b1, Wc0, bc0, Wc1, bc1, WgT, WcT, bias_g, bias_c,
                     colsum);
  hipLaunchKernelGGL(k1_adj, dim3(16,16,16), dim3(256), 0, stream,
                     adj, adjbf, adjTbf, colsum, rowsum);
  hipLaunchKernelGGL(k1c_dinv, dim3(64), dim3(256), 0, stream, colsum, rowsum);
  hipLaunchKernelGGL(k1b_x, dim3(256), dim3(256), 0, stream, inp, hx, XC, Xt, XC2);
  hipLaunchKernelGGL(k2_y, dim3(512), dim3(256), 0, stream,
                     adjbf, adjTbf, Xt, inp, hx, colsum, rowsum, XC, XC2);
  hipLaunchKernelGGL(k3_gates, dim3(256), dim3(256), 0, stream,
                     XC, WgT, bias_g, hx, XC2, St, uBuf);
  hipLaunchKernelGGL(k4_z, dim3(512), dim3(256), 0, stream,
                     adjbf, adjTbf, St, colsum, rowsum, XC2);
  hipLaunchKernelGGL(k5_out, dim3(256), dim3(256), 0, stream,
                     XC2, WcT, bias_c, uBuf, hx, out);
}

// Round 4
// 117.399 us; speedup vs baseline: 1.0598x; 1.0598x over previous
//
#include <hip/hip_runtime.h>
#include <hip/hip_bf16.h>

typedef unsigned short u16;
typedef unsigned int u32;
typedef __bf16 bf16x8 __attribute__((ext_vector_type(8)));
typedef float floatx4 __attribute__((ext_vector_type(4)));

#define MFMA16(a,b,c) __builtin_amdgcn_mfma_f32_16x16x32_bf16((a),(b),(c),0,0,0)
#define AS1 __attribute__((address_space(1)))
#define AS3 __attribute__((address_space(3)))
#define VMCNT0 asm volatile("s_waitcnt vmcnt(0)" ::: "memory")

__device__ __forceinline__ void gl16(const void* g, void* l){
  __builtin_amdgcn_global_load_lds((const AS1 void*)g, (AS3 void*)l, 16, 0, 0);
}

__device__ __forceinline__ u16 f2bf(float f){
  u32 u = __builtin_bit_cast(u32, f);
  u += 0x7FFFu + ((u >> 16) & 1u);
  return (u16)(u >> 16);
}
__device__ __forceinline__ float bf2f(u16 h){
  u32 u = ((u32)h) << 16;
  return __builtin_bit_cast(float, u);
}
__device__ __forceinline__ bf16x8 ldfrag(const u16* p){
  return *(const bf16x8*)p;
}

// ---------------- KA: merged k0 (weights+bias+zero sums) and k1b (X staging) ----
// blocks [0,256): k1b work; blocks [256,544): k0 work
__global__ __launch_bounds__(256) void ka_prep(
    const float* __restrict__ inp, const float* __restrict__ hx,
    const float* __restrict__ W0, const float* __restrict__ b0,
    const float* __restrict__ W1, const float* __restrict__ b1,
    const float* __restrict__ Wc0, const float* __restrict__ bc0,
    const float* __restrict__ Wc1, const float* __restrict__ bc1,
    u16* __restrict__ WgT, u16* __restrict__ WcT,
    float* __restrict__ bias_g, float* __restrict__ bias_c,
    float* __restrict__ sums,
    u16* __restrict__ XC, u16* __restrict__ Xt, u16* __restrict__ XC2){
  __shared__ u16 XT[128][80];
  int t = threadIdx.x;
  if (blockIdx.x >= 256) {
    int id = (blockIdx.x - 256)*256 + t;
    if (id < 32768) sums[id] = 0.0f;
    if (id < 128*384) {
      int n = id / 384, k = id % 384;
      float v;
      if (k < 128)       v = W0[(k*3+0)*128 + n] + W1[(k*3+0)*128 + n];
      else if (k < 256){ int f = k-128; v = W0[(f*3+1)*128+n] + W0[(f*3+2)*128+n]; }
      else             { int f = k-256; v = W1[(f*3+1)*128+n] + W1[(f*3+2)*128+n]; }
      WgT[(size_t)n*384 + k] = f2bf(v);
    } else {
      int id2 = id - 128*384;
      int n = id2 / 384, k = id2 % 384;
      float v;
      if (k < 128)       v = Wc0[(k*3+0)*64 + n] + Wc1[(k*3+0)*64 + n];
      else if (k < 256){ int f = k-128; v = Wc0[(f*3+1)*64+n] + Wc0[(f*3+2)*64+n]; }
      else             { int f = k-256; v = Wc1[(f*3+1)*64+n] + Wc1[(f*3+2)*64+n]; }
      WcT[(size_t)n*384 + k] = f2bf(v);
    }
    if (blockIdx.x == 256) {
      if (t < 128) bias_g[t] = b0[t] + b1[t];
      if (t < 64)  bias_c[t] = bc0[t] + bc1[t];
    }
    return;
  }
  // ---- k1b part ----
  int r = t >> 2;
  int row = blockIdx.x*64 + r;
  int fq = t & 3;
  const float4* ip = (const float4*)(inp + (size_t)row*64 + fq*16);
  const float4* hp = (const float4*)(hx  + (size_t)row*64 + fq*16);
  float iv[16], hv[16];
  #pragma unroll
  for (int q=0;q<4;q++){
    float4 a = ip[q]; iv[4*q]=a.x; iv[4*q+1]=a.y; iv[4*q+2]=a.z; iv[4*q+3]=a.w;
    float4 c = hp[q]; hv[4*q]=c.x; hv[4*q+1]=c.y; hv[4*q+2]=c.z; hv[4*q+3]=c.w;
  }
  u16 ib[16], hb[16];
  #pragma unroll
  for (int q=0;q<16;q++){ ib[q]=f2bf(iv[q]); hb[q]=f2bf(hv[q]); }
  u32 pi[8], ph[8];
  #pragma unroll
  for (int q=0;q<8;q++){
    pi[q] = (u32)ib[2*q] | ((u32)ib[2*q+1]<<16);
    ph[q] = (u32)hb[2*q] | ((u32)hb[2*q+1]<<16);
  }
  size_t rbase = (size_t)row*384;
  *(uint4*)(XC + rbase + fq*16)          = make_uint4(pi[0],pi[1],pi[2],pi[3]);
  *(uint4*)(XC + rbase + fq*16 + 8)      = make_uint4(pi[4],pi[5],pi[6],pi[7]);
  *(uint4*)(XC + rbase + 64 + fq*16)     = make_uint4(ph[0],ph[1],ph[2],ph[3]);
  *(uint4*)(XC + rbase + 64 + fq*16 + 8) = make_uint4(ph[4],ph[5],ph[6],ph[7]);
  *(uint4*)(XC2 + rbase + fq*16)         = make_uint4(pi[0],pi[1],pi[2],pi[3]);
  *(uint4*)(XC2 + rbase + fq*16 + 8)     = make_uint4(pi[4],pi[5],pi[6],pi[7]);
  #pragma unroll
  for (int q=0;q<16;q++){
    XT[fq*16+q][r]      = ib[q];
    XT[64+fq*16+q][r]   = hb[q];
  }
  __syncthreads();
  int feat = t >> 1, half = t & 1;
  int b = blockIdx.x >> 4, n0 = (blockIdx.x & 15)*64;
  const uint4* src = (const uint4*)&XT[feat][half*32];
  uint4* dst = (uint4*)(Xt + (size_t)b*131072 + (size_t)feat*1024 + n0 + half*32);
  dst[0]=src[0]; dst[1]=src[1]; dst[2]=src[2]; dst[3]=src[3];
}

// ---------------- K1: adj pass: row/col sums + bf16 copy + transposed bf16 copy
__global__ __launch_bounds__(256) void k1_adj(const float* __restrict__ adj,
    u16* __restrict__ adjbf, u16* __restrict__ adjTbf,
    float* __restrict__ colsum, float* __restrict__ rowsum){
  __shared__ u16 lt[64][72];
  int b = blockIdx.z;
  int i0 = blockIdx.y << 6, j0 = blockIdx.x << 6;
  int t = threadIdx.x;
  int r = t >> 2, cq = t & 3;
  size_t base = ((size_t)b << 20);
  const float4* s4 = (const float4*)(adj + base + (size_t)(i0 + r)*1024 + j0 + (cq<<4));
  float v[16];
  #pragma unroll
  for (int q = 0; q < 4; q++) {
    float4 f = s4[q];
    v[4*q]=f.x; v[4*q+1]=f.y; v[4*q+2]=f.z; v[4*q+3]=f.w;
  }
  u32 u8[8];
  #pragma unroll
  for (int q = 0; q < 8; q++)
    u8[q] = (u32)f2bf(v[2*q]) | ((u32)f2bf(v[2*q+1]) << 16);
  uint4* d = (uint4*)(adjbf + base + (size_t)(i0 + r)*1024 + j0 + (cq<<4));
  d[0] = make_uint4(u8[0],u8[1],u8[2],u8[3]);
  d[1] = make_uint4(u8[4],u8[5],u8[6],u8[7]);
  float rs = 0.f;
  #pragma unroll
  for (int q = 0; q < 16; q++) rs += v[q];
  rs += __shfl_down(rs, 1, 64);
  rs += __shfl_down(rs, 2, 64);
  if (cq == 0) atomicAdd(&rowsum[b*1024 + i0 + r], rs);
  #pragma unroll
  for (int q = 0; q < 16; q++)
    lt[(cq<<4) + q][r] = (u16)(u8[q>>1] >> ((q&1)*16));
  __syncthreads();
  uint4 q0 = *(const uint4*)&lt[r][(cq<<4)];
  uint4 q1 = *(const uint4*)&lt[r][(cq<<4) + 8];
  uint4* dT = (uint4*)(adjTbf + base + (size_t)(j0 + r)*1024 + i0 + (cq<<4));
  dT[0] = q0; dT[1] = q1;
  u32 w8[8] = {q0.x,q0.y,q0.z,q0.w,q1.x,q1.y,q1.z,q1.w};
  float cs = 0.f;
  #pragma unroll
  for (int q = 0; q < 8; q++)
    cs += bf2f((u16)(w8[q] & 0xFFFFu)) + bf2f((u16)(w8[q] >> 16));
  cs += __shfl_down(cs, 1, 64);
  cs += __shfl_down(cs, 2, 64);
  if (cq == 0) atomicAdd(&colsum[b*1024 + j0 + r], cs);
}

// ---------------- K2: Y = (1/(sum+1)) * ((adj(+T) @ X) + X) ; tile 32x128, grid 1024
__global__ __launch_bounds__(256) void k2_y(const u16* __restrict__ adjbf,
    const u16* __restrict__ adjTbf, const u16* __restrict__ Xt,
    const float* __restrict__ inp, const float* __restrict__ hx,
    const float* __restrict__ colsum, const float* __restrict__ rowsum,
    u16* __restrict__ XC, u16* __restrict__ XC2){
  __shared__ u16 Al[2][32*32];    // 2KB per buf
  __shared__ u16 Bl[2][128*32];   // 8KB per buf
  int bid0 = blockIdx.x;
  int bid = (bid0 & 7)*128 + (bid0 >> 3);     // XCD chunked swizzle (1024 = 8*128)
  int mt = bid & 31, b = (bid>>5)&15, T = bid>>9;
  const u16* A = (T ? adjTbf : adjbf) + ((size_t)b<<20) + (size_t)mt*32*1024;
  const float* sums = (T ? rowsum : colsum) + b*1024;
  const u16* Xb = Xt + (size_t)b*131072;
  int t = threadIdx.x, w = t>>6, l = t&63, lr = l&15, lg = l>>4;
  int wr = w>>1, wc = w&1;
  // staging sources: A 2KB by waves 0-1; B 8KB = 2 chunks of 1KB per wave
  const char* Ag  = (const char*)A  + (size_t)(w*16 + (l>>2))*2048 + (l&3)*16;
  const char* Bg0 = (const char*)Xb + (size_t)(w*32      + (l>>2))*2048 + (l&3)*16;
  const char* Bg1 = (const char*)Xb + (size_t)(w*32 + 16 + (l>>2))*2048 + (l&3)*16;
  floatx4 acc[4] = {};
  // prologue
  if (w < 2) gl16(Ag, (char*)Al[0] + w*1024);
  gl16(Bg0, (char*)Bl[0] + w*2048);
  gl16(Bg1, (char*)Bl[0] + w*2048 + 1024);
  VMCNT0; __syncthreads();
  int cur = 0;
  for (int kk = 32; kk < 1024; kk += 32){
    if (w < 2) gl16(Ag + kk*2, (char*)Al[cur^1] + w*1024);
    gl16(Bg0 + kk*2, (char*)Bl[cur^1] + w*2048);
    gl16(Bg1 + kk*2, (char*)Bl[cur^1] + w*2048 + 1024);
    bf16x8 af = *(const bf16x8*)((const char*)Al[cur] + (size_t)(wr*16+lr)*64 + lg*16);
    bf16x8 bfr[4];
    #pragma unroll
    for (int nf = 0; nf < 4; nf++)
      bfr[nf] = *(const bf16x8*)((const char*)Bl[cur] + (size_t)(wc*64+nf*16+lr)*64 + lg*16);
    #pragma unroll
    for (int nf = 0; nf < 4; nf++)
      acc[nf] = MFMA16(af, bfr[nf], acc[nf]);
    VMCNT0; __syncthreads();
    cur ^= 1;
  }
  {
    bf16x8 af = *(const bf16x8*)((const char*)Al[cur] + (size_t)(wr*16+lr)*64 + lg*16);
    bf16x8 bfr[4];
    #pragma unroll
    for (int nf = 0; nf < 4; nf++)
      bfr[nf] = *(const bf16x8*)((const char*)Bl[cur] + (size_t)(wc*64+nf*16+lr)*64 + lg*16);
    #pragma unroll
    for (int nf = 0; nf < 4; nf++)
      acc[nf] = MFMA16(af, bfr[nf], acc[nf]);
  }
  int outcol = T ? 256 : 128;
  #pragma unroll
  for (int nf = 0; nf < 4; nf++) {
    #pragma unroll
    for (int rr = 0; rr < 4; rr++) {
      int row = mt*32 + wr*16 + lg*4 + rr;
      int col = wc*64 + nf*16 + lr;
      float dinv = 1.0f / (sums[row] + 1.0f);
      float xv = (col < 64) ? inp[(size_t)(b*1024+row)*64 + col]
                            : hx [(size_t)(b*1024+row)*64 + (col-64)];
      float v2 = (acc[nf][rr] + xv) * dinv;
      u16 bv = f2bf(v2);
      size_t grow = (size_t)(b*1024 + row)*384;
      XC[grow + outcol + col] = bv;
      if (col < 64) XC2[grow + outcol + col] = bv;
    }
  }
}

// ---------------- K3: gates GEMM + sigmoid; emit u, S row-major + St via LDS transpose
__global__ __launch_bounds__(256) void k3_gates(const u16* __restrict__ XC,
    const u16* __restrict__ WgT, const float* __restrict__ bias_g,
    const float* __restrict__ hx, u16* __restrict__ XC2,
    u16* __restrict__ St, float* __restrict__ uBuf){
  __shared__ u16 SL[64][80];
  int t = threadIdx.x, w = t >> 6, l = t & 63, lr = l & 15, lg = l >> 4;
  int r0 = blockIdx.x*64 + w*16;
  floatx4 acc[8] = {};
  for (int kk = 0; kk < 384; kk += 32) {
    int ko = kk + lg*8;
    bf16x8 a = ldfrag(XC + (size_t)(r0 + lr)*384 + ko);
    #pragma unroll
    for (int nf = 0; nf < 8; nf++)
      acc[nf] = MFMA16(a, ldfrag(WgT + (size_t)(nf*16+lr)*384 + ko), acc[nf]);
  }
  #pragma unroll
  for (int nf = 0; nf < 8; nf++) {
    #pragma unroll
    for (int rr = 0; rr < 4; rr++) {
      int row = r0 + lg*4 + rr;
      int col = nf*16 + lr;
      float pre = acc[nf][rr] + bias_g[col];
      float s = 1.0f / (1.0f + __expf(-pre));
      if (col < 64) {
        float sh = s * hx[(size_t)row*64 + col];
        u16 bv = f2bf(sh);
        XC2[(size_t)row*384 + 64 + col] = bv;
        SL[col][w*16 + lg*4 + rr] = bv;
      } else {
        uBuf[(size_t)row*64 + (col-64)] = s;
      }
    }
  }
  __syncthreads();
  int col = t >> 2, q = t & 3;
  int gb = blockIdx.x >> 4, n0 = (blockIdx.x & 15)*64;
  const uint4* src = (const uint4*)&SL[col][q*16];
  uint4* dst = (uint4*)(St + (size_t)gb*65536 + (size_t)col*1024 + n0 + q*16);
  dst[0]=src[0]; dst[1]=src[1];
}

// ---------------- K4: Z = (1/(sum+1)) * ((adj(+T) @ S) + S) ; tile 32x64, grid 1024
__global__ __launch_bounds__(256) void k4_z(const u16* __restrict__ adjbf,
    const u16* __restrict__ adjTbf, const u16* __restrict__ St,
    const float* __restrict__ colsum, const float* __restrict__ rowsum,
    u16* __restrict__ XC2){
  __shared__ u16 Al[2][32*32];   // 2KB per buf
  __shared__ u16 Bl[2][64*32];   // 4KB per buf
  int bid0 = blockIdx.x;
  int bid = (bid0 & 7)*128 + (bid0 >> 3);
  int mt = bid & 31, b = (bid>>5)&15, T = bid>>9;
  const u16* A = (T ? adjTbf : adjbf) + ((size_t)b<<20) + (size_t)mt*32*1024;
  const float* sums = (T ? rowsum : colsum) + b*1024;
  const u16* Sb = St + (size_t)b*65536;
  int t = threadIdx.x, w = t>>6, l = t&63, lr = l&15, lg = l>>4;
  int wr = w>>1, wc = w&1;
  const char* Ag = (const char*)A  + (size_t)(w*16 + (l>>2))*2048 + (l&3)*16;
  const char* Bg = (const char*)Sb + (size_t)(w*16 + (l>>2))*2048 + (l&3)*16;
  floatx4 acc[2] = {};
  if (w < 2) gl16(Ag, (char*)Al[0] + w*1024);
  gl16(Bg, (char*)Bl[0] + w*1024);
  VMCNT0; __syncthreads();
  int cur = 0;
  for (int kk = 32; kk < 1024; kk += 32){
    if (w < 2) gl16(Ag + kk*2, (char*)Al[cur^1] + w*1024);
    gl16(Bg + kk*2, (char*)Bl[cur^1] + w*1024);
    bf16x8 af = *(const bf16x8*)((const char*)Al[cur] + (size_t)(wr*16+lr)*64 + lg*16);
    bf16x8 bfr[2];
    #pragma unroll
    for (int nf = 0; nf < 2; nf++)
      bfr[nf] = *(const bf16x8*)((const char*)Bl[cur] + (size_t)(wc*32+nf*16+lr)*64 + lg*16);
    #pragma unroll
    for (int nf = 0; nf < 2; nf++)
      acc[nf] = MFMA16(af, bfr[nf], acc[nf]);
    VMCNT0; __syncthreads();
    cur ^= 1;
  }
  {
    bf16x8 af = *(const bf16x8*)((const char*)Al[cur] + (size_t)(wr*16+lr)*64 + lg*16);
    bf16x8 bfr[2];
    #pragma unroll
    for (int nf = 0; nf < 2; nf++)
      bfr[nf] = *(const bf16x8*)((const char*)Bl[cur] + (size_t)(wc*32+nf*16+lr)*64 + lg*16);
    #pragma unroll
    for (int nf = 0; nf < 2; nf++)
      acc[nf] = MFMA16(af, bfr[nf], acc[nf]);
  }
  int zcol = T ? 320 : 192;
  #pragma unroll
  for (int nf = 0; nf < 2; nf++) {
    #pragma unroll
    for (int rr = 0; rr < 4; rr++) {
      int row = mt*32 + wr*16 + lg*4 + rr;
      int col = wc*32 + nf*16 + lr;
      float dinv = 1.0f / (sums[row] + 1.0f);
      size_t grow = (size_t)(b*1024 + row)*384;
      float sval = bf2f(XC2[grow + 64 + col]);
      float v2 = (acc[nf][rr] + sval) * dinv;
      XC2[grow + zcol + col] = f2bf(v2);
    }
  }
}

// ---------------- K5: candidate GEMM + tanh + GRU update -> out
__global__ __launch_bounds__(256) void k5_out(const u16* __restrict__ XC2,
    const u16* __restrict__ WcT, const float* __restrict__ bias_c,
    const float* __restrict__ uBuf, const float* __restrict__ hx,
    float* __restrict__ out){
  int w = threadIdx.x >> 6, l = threadIdx.x & 63, lr = l & 15, lg = l >> 4;
  int r0 = blockIdx.x*64 + w*16;
  floatx4 acc[4] = {};
  for (int kk = 0; kk < 384; kk += 32) {
    int ko = kk + lg*8;
    bf16x8 a = ldfrag(XC2 + (size_t)(r0 + lr)*384 + ko);
    #pragma unroll
    for (int nf = 0; nf < 4; nf++)
      acc[nf] = MFMA16(a, ldfrag(WcT + (size_t)(nf*16+lr)*384 + ko), acc[nf]);
  }
  #pragma unroll
  for (int nf = 0; nf < 4; nf++) {
    #pragma unroll
    for (int rr = 0; rr < 4; rr++) {
      int row = r0 + lg*4 + rr;
      int col = nf*16 + lr;
      float pre = acc[nf][rr] + bias_c[col];
      pre = fminf(fmaxf(pre, -15.f), 15.f);
      float e2 = __expf(2.0f*pre);
      float c = (e2 - 1.0f) / (e2 + 1.0f);
      float u = uBuf[(size_t)row*64 + col];
      float h = hx[(size_t)row*64 + col];
      out[(size_t)row*64 + col] = u*h + (1.0f - u)*c;
    }
  }
}

extern "C" void kernel_launch(void* const* d_in, const int* in_sizes, int n_in,
                              void* d_out, int out_size, void* d_ws, size_t ws_size,
                              hipStream_t stream) {
  (void)in_sizes; (void)n_in; (void)out_size; (void)ws_size;
  const float* inp = (const float*)d_in[0];
  const float* hx  = (const float*)d_in[1];
  const float* adj = (const float*)d_in[2];
  const float* W0  = (const float*)d_in[3];
  const float* b0  = (const float*)d_in[4];
  const float* W1  = (const float*)d_in[5];
  const float* b1  = (const float*)d_in[6];
  const float* Wc0 = (const float*)d_in[7];
  const float* bc0 = (const float*)d_in[8];
  const float* Wc1 = (const float*)d_in[9];
  const float* bc1 = (const float*)d_in[10];
  float* out = (float*)d_out;
  char* ws = (char*)d_ws;

  float* colsum = (float*)(ws + 0);
  float* rowsum = (float*)(ws + 65536);
  u16* adjbf  = (u16*)(ws + 131072);
  u16* adjTbf = (u16*)(ws + 33685504);
  u16* Xt     = (u16*)(ws + 67239936);
  u16* XC     = (u16*)(ws + 71434240);
  u16* XC2    = (u16*)(ws + 84017152);
  u16* St     = (u16*)(ws + 96600064);
  float* uBuf = (float*)(ws + 98697216);
  u16* WgT    = (u16*)(ws + 102891520);
  u16* WcT    = (u16*)(ws + 102989824);
  float* bias_g = (float*)(ws + 103038976);
  float* bias_c = (float*)(ws + 103039488);

  hipLaunchKernelGGL(ka_prep, dim3(544), dim3(256), 0, stream,
                     inp, hx, W0, b0, W1, b1, Wc0, bc0, Wc1, bc1,
                     WgT, WcT, bias_g, bias_c, colsum, XC, Xt, XC2);
  hipLaunchKernelGGL(k1_adj, dim3(16,16,16), dim3(256), 0, stream,
                     adj, adjbf, adjTbf, colsum, rowsum);
  hipLaunchKernelGGL(k2_y, dim3(1024), dim3(256), 0, stream,
                     adjbf, adjTbf, Xt, inp, hx, colsum, rowsum, XC, XC2);
  hipLaunchKernelGGL(k3_gates, dim3(256), dim3(256), 0, stream,
                     XC, WgT, bias_g, hx, XC2, St, uBuf);
  hipLaunchKernelGGL(k4_z, dim3(1024), dim3(256), 0, stream,
                     adjbf, adjTbf, St, colsum, rowsum, XC2);
  hipLaunchKernelGGL(k5_out, dim3(256), dim3(256), 0, stream,
                     XC2, WcT, bias_c, uBuf, hx, out);
}

// Round 5
// 113.385 us; speedup vs baseline: 1.0973x; 1.0354x over previous
//
#include <hip/hip_runtime.h>
#include <hip/hip_bf16.h>

typedef unsigned short u16;
typedef unsigned int u32;
typedef __bf16 bf16x8 __attribute__((ext_vector_type(8)));
typedef float floatx4 __attribute__((ext_vector_type(4)));

#define MFMA16(a,b,c) __builtin_amdgcn_mfma_f32_16x16x32_bf16((a),(b),(c),0,0,0)
#define AS1 __attribute__((address_space(1)))
#define AS3 __attribute__((address_space(3)))
#define VMCNT0 asm volatile("s_waitcnt vmcnt(0)" ::: "memory")

__device__ __forceinline__ void gl16(const void* g, void* l){
  __builtin_amdgcn_global_load_lds((const AS1 void*)g, (AS3 void*)l, 16, 0, 0);
}

__device__ __forceinline__ u16 f2bf(float f){
  u32 u = __builtin_bit_cast(u32, f);
  u += 0x7FFFu + ((u >> 16) & 1u);
  return (u16)(u >> 16);
}
__device__ __forceinline__ float bf2f(u16 h){
  u32 u = ((u32)h) << 16;
  return __builtin_bit_cast(float, u);
}
__device__ __forceinline__ bf16x8 ldfrag(const u16* p){
  return *(const bf16x8*)p;
}

// ---------------- KA: merged k0 (weights+bias+zero sums) and k1b (X staging) ----
__global__ __launch_bounds__(256) void ka_prep(
    const float* __restrict__ inp, const float* __restrict__ hx,
    const float* __restrict__ W0, const float* __restrict__ b0,
    const float* __restrict__ W1, const float* __restrict__ b1,
    const float* __restrict__ Wc0, const float* __restrict__ bc0,
    const float* __restrict__ Wc1, const float* __restrict__ bc1,
    u16* __restrict__ WgT, u16* __restrict__ WcT,
    float* __restrict__ bias_g, float* __restrict__ bias_c,
    float* __restrict__ sums,
    u16* __restrict__ XC, u16* __restrict__ Xt, u16* __restrict__ XC2){
  __shared__ u16 XT[128][80];
  int t = threadIdx.x;
  if (blockIdx.x >= 256) {
    int id = (blockIdx.x - 256)*256 + t;
    if (id < 32768) sums[id] = 0.0f;
    if (id < 128*384) {
      int n = id / 384, k = id % 384;
      float v;
      if (k < 128)       v = W0[(k*3+0)*128 + n] + W1[(k*3+0)*128 + n];
      else if (k < 256){ int f = k-128; v = W0[(f*3+1)*128+n] + W0[(f*3+2)*128+n]; }
      else             { int f = k-256; v = W1[(f*3+1)*128+n] + W1[(f*3+2)*128+n]; }
      WgT[(size_t)n*384 + k] = f2bf(v);
    } else {
      int id2 = id - 128*384;
      int n = id2 / 384, k = id2 % 384;
      float v;
      if (k < 128)       v = Wc0[(k*3+0)*64 + n] + Wc1[(k*3+0)*64 + n];
      else if (k < 256){ int f = k-128; v = Wc0[(f*3+1)*64+n] + Wc0[(f*3+2)*64+n]; }
      else             { int f = k-256; v = Wc1[(f*3+1)*64+n] + Wc1[(f*3+2)*64+n]; }
      WcT[(size_t)n*384 + k] = f2bf(v);
    }
    if (blockIdx.x == 256) {
      if (t < 128) bias_g[t] = b0[t] + b1[t];
      if (t < 64)  bias_c[t] = bc0[t] + bc1[t];
    }
    return;
  }
  // ---- k1b part ----
  int r = t >> 2;
  int row = blockIdx.x*64 + r;
  int fq = t & 3;
  const float4* ip = (const float4*)(inp + (size_t)row*64 + fq*16);
  const float4* hp = (const float4*)(hx  + (size_t)row*64 + fq*16);
  float iv[16], hv[16];
  #pragma unroll
  for (int q=0;q<4;q++){
    float4 a = ip[q]; iv[4*q]=a.x; iv[4*q+1]=a.y; iv[4*q+2]=a.z; iv[4*q+3]=a.w;
    float4 c = hp[q]; hv[4*q]=c.x; hv[4*q+1]=c.y; hv[4*q+2]=c.z; hv[4*q+3]=c.w;
  }
  u16 ib[16], hb[16];
  #pragma unroll
  for (int q=0;q<16;q++){ ib[q]=f2bf(iv[q]); hb[q]=f2bf(hv[q]); }
  u32 pi[8], ph[8];
  #pragma unroll
  for (int q=0;q<8;q++){
    pi[q] = (u32)ib[2*q] | ((u32)ib[2*q+1]<<16);
    ph[q] = (u32)hb[2*q] | ((u32)hb[2*q+1]<<16);
  }
  size_t rbase = (size_t)row*384;
  *(uint4*)(XC + rbase + fq*16)          = make_uint4(pi[0],pi[1],pi[2],pi[3]);
  *(uint4*)(XC + rbase + fq*16 + 8)      = make_uint4(pi[4],pi[5],pi[6],pi[7]);
  *(uint4*)(XC + rbase + 64 + fq*16)     = make_uint4(ph[0],ph[1],ph[2],ph[3]);
  *(uint4*)(XC + rbase + 64 + fq*16 + 8) = make_uint4(ph[4],ph[5],ph[6],ph[7]);
  *(uint4*)(XC2 + rbase + fq*16)         = make_uint4(pi[0],pi[1],pi[2],pi[3]);
  *(uint4*)(XC2 + rbase + fq*16 + 8)     = make_uint4(pi[4],pi[5],pi[6],pi[7]);
  #pragma unroll
  for (int q=0;q<16;q++){
    XT[fq*16+q][r]      = ib[q];
    XT[64+fq*16+q][r]   = hb[q];
  }
  __syncthreads();
  int feat = t >> 1, half = t & 1;
  int b = blockIdx.x >> 4, n0 = (blockIdx.x & 15)*64;
  const uint4* src = (const uint4*)&XT[feat][half*32];
  uint4* dst = (uint4*)(Xt + (size_t)b*131072 + (size_t)feat*1024 + n0 + half*32);
  dst[0]=src[0]; dst[1]=src[1]; dst[2]=src[2]; dst[3]=src[3];
}

// ---------------- K1: adj pass: row/col sums + bf16 copy + transposed bf16 copy
__global__ __launch_bounds__(256) void k1_adj(const float* __restrict__ adj,
    u16* __restrict__ adjbf, u16* __restrict__ adjTbf,
    float* __restrict__ colsum, float* __restrict__ rowsum){
  __shared__ u16 lt[64][72];
  int b = blockIdx.z;
  int i0 = blockIdx.y << 6, j0 = blockIdx.x << 6;
  int t = threadIdx.x;
  int r = t >> 2, cq = t & 3;
  size_t base = ((size_t)b << 20);
  const float4* s4 = (const float4*)(adj + base + (size_t)(i0 + r)*1024 + j0 + (cq<<4));
  float v[16];
  #pragma unroll
  for (int q = 0; q < 4; q++) {
    float4 f = s4[q];
    v[4*q]=f.x; v[4*q+1]=f.y; v[4*q+2]=f.z; v[4*q+3]=f.w;
  }
  u32 u8[8];
  #pragma unroll
  for (int q = 0; q < 8; q++)
    u8[q] = (u32)f2bf(v[2*q]) | ((u32)f2bf(v[2*q+1]) << 16);
  uint4* d = (uint4*)(adjbf + base + (size_t)(i0 + r)*1024 + j0 + (cq<<4));
  d[0] = make_uint4(u8[0],u8[1],u8[2],u8[3]);
  d[1] = make_uint4(u8[4],u8[5],u8[6],u8[7]);
  float rs = 0.f;
  #pragma unroll
  for (int q = 0; q < 16; q++) rs += v[q];
  rs += __shfl_down(rs, 1, 64);
  rs += __shfl_down(rs, 2, 64);
  if (cq == 0) atomicAdd(&rowsum[b*1024 + i0 + r], rs);
  #pragma unroll
  for (int q = 0; q < 16; q++)
    lt[(cq<<4) + q][r] = (u16)(u8[q>>1] >> ((q&1)*16));
  __syncthreads();
  uint4 q0 = *(const uint4*)&lt[r][(cq<<4)];
  uint4 q1 = *(const uint4*)&lt[r][(cq<<4) + 8];
  uint4* dT = (uint4*)(adjTbf + base + (size_t)(j0 + r)*1024 + i0 + (cq<<4));
  dT[0] = q0; dT[1] = q1;
  u32 w8[8] = {q0.x,q0.y,q0.z,q0.w,q1.x,q1.y,q1.z,q1.w};
  float cs = 0.f;
  #pragma unroll
  for (int q = 0; q < 8; q++)
    cs += bf2f((u16)(w8[q] & 0xFFFFu)) + bf2f((u16)(w8[q] >> 16));
  cs += __shfl_down(cs, 1, 64);
  cs += __shfl_down(cs, 2, 64);
  if (cq == 0) atomicAdd(&colsum[b*1024 + j0 + r], cs);
}

// ---------------- K2: Y = (1/(sum+1)) * ((adj(+T) @ X) + X)
// tile 32x128, BK=64, XOR-swizzled LDS (byte ^= (row&7)<<4), grid 1024
__global__ __launch_bounds__(256) void k2_y(const u16* __restrict__ adjbf,
    const u16* __restrict__ adjTbf, const u16* __restrict__ Xt,
    const float* __restrict__ inp, const float* __restrict__ hx,
    const float* __restrict__ colsum, const float* __restrict__ rowsum,
    u16* __restrict__ XC, u16* __restrict__ XC2){
  __shared__ u16 Al[2][32*64];    // 4KB per buf
  __shared__ u16 Bl[2][128*64];   // 16KB per buf
  int bid0 = blockIdx.x;
  int bid = (bid0 & 7)*128 + (bid0 >> 3);     // XCD chunked swizzle
  int mt = bid & 31, b = (bid>>5)&15, T = bid>>9;
  const u16* A = (T ? adjTbf : adjbf) + ((size_t)b<<20) + (size_t)mt*32*1024;
  const float* sums = (T ? rowsum : colsum) + b*1024;
  const u16* Xb = Xt + (size_t)b*131072;
  int t = threadIdx.x, w = t>>6, l = t&63, lr = l&15, lg = l>>4;
  int wm = w>>1, wn = w&1;
  int swz = ((l&7) ^ ((l>>3)&7)) << 4;        // pre-swizzled global source
  // A: wave w stages rows w*8..+8 (1 gl16); B: wave w stages feats w*32..+32 (4 gl16)
  const char* Ag = (const char*)A  + (size_t)(w*8  + (l>>3))*2048 + swz;
  const char* Bg = (const char*)Xb + (size_t)(w*32 + (l>>3))*2048 + swz;
  floatx4 acc[4] = {};
  gl16(Ag, (char*)Al[0] + w*1024);
  #pragma unroll
  for (int q=0;q<4;q++)
    gl16(Bg + q*16384, (char*)Bl[0] + w*4096 + q*1024);
  VMCNT0; __syncthreads();
  int cur = 0;
  for (int kk = 64; kk < 1024; kk += 64){
    gl16(Ag + kk*2, (char*)Al[cur^1] + w*1024);
    #pragma unroll
    for (int q=0;q<4;q++)
      gl16(Bg + q*16384 + kk*2, (char*)Bl[cur^1] + w*4096 + q*1024);
    #pragma unroll
    for (int kf=0; kf<2; kf++){
      int fo = (kf*64 + lg*16) ^ ((lr&7)<<4);
      bf16x8 af = *(const bf16x8*)((const char*)Al[cur] + (wm*16+lr)*128 + fo);
      #pragma unroll
      for (int nf=0; nf<4; nf++){
        bf16x8 bfr = *(const bf16x8*)((const char*)Bl[cur] + (wn*64+nf*16+lr)*128 + fo);
        acc[nf] = MFMA16(af, bfr, acc[nf]);
      }
    }
    VMCNT0; __syncthreads();
    cur ^= 1;
  }
  #pragma unroll
  for (int kf=0; kf<2; kf++){
    int fo = (kf*64 + lg*16) ^ ((lr&7)<<4);
    bf16x8 af = *(const bf16x8*)((const char*)Al[cur] + (wm*16+lr)*128 + fo);
    #pragma unroll
    for (int nf=0; nf<4; nf++){
      bf16x8 bfr = *(const bf16x8*)((const char*)Bl[cur] + (wn*64+nf*16+lr)*128 + fo);
      acc[nf] = MFMA16(af, bfr, acc[nf]);
    }
  }
  int outcol = T ? 256 : 128;
  #pragma unroll
  for (int nf = 0; nf < 4; nf++) {
    #pragma unroll
    for (int rr = 0; rr < 4; rr++) {
      int row = mt*32 + wm*16 + lg*4 + rr;
      int col = wn*64 + nf*16 + lr;
      float dinv = 1.0f / (sums[row] + 1.0f);
      float xv = (col < 64) ? inp[(size_t)(b*1024+row)*64 + col]
                            : hx [(size_t)(b*1024+row)*64 + (col-64)];
      float v2 = (acc[nf][rr] + xv) * dinv;
      u16 bv = f2bf(v2);
      size_t grow = (size_t)(b*1024 + row)*384;
      XC[grow + outcol + col] = bv;
      if (col < 64) XC2[grow + outcol + col] = bv;
    }
  }
}

// ---------------- K3: gates GEMM + sigmoid; emit u, S row-major + St via LDS transpose
__global__ __launch_bounds__(256) void k3_gates(const u16* __restrict__ XC,
    const u16* __restrict__ WgT, const float* __restrict__ bias_g,
    const float* __restrict__ hx, u16* __restrict__ XC2,
    u16* __restrict__ St, float* __restrict__ uBuf){
  __shared__ u16 SL[64][80];
  int t = threadIdx.x, w = t >> 6, l = t & 63, lr = l & 15, lg = l >> 4;
  int r0 = blockIdx.x*64 + w*16;
  floatx4 acc[8] = {};
  for (int kk = 0; kk < 384; kk += 32) {
    int ko = kk + lg*8;
    bf16x8 a = ldfrag(XC + (size_t)(r0 + lr)*384 + ko);
    #pragma unroll
    for (int nf = 0; nf < 8; nf++)
      acc[nf] = MFMA16(a, ldfrag(WgT + (size_t)(nf*16+lr)*384 + ko), acc[nf]);
  }
  #pragma unroll
  for (int nf = 0; nf < 8; nf++) {
    #pragma unroll
    for (int rr = 0; rr < 4; rr++) {
      int row = r0 + lg*4 + rr;
      int col = nf*16 + lr;
      float pre = acc[nf][rr] + bias_g[col];
      float s = 1.0f / (1.0f + __expf(-pre));
      if (col < 64) {
        float sh = s * hx[(size_t)row*64 + col];
        u16 bv = f2bf(sh);
        XC2[(size_t)row*384 + 64 + col] = bv;
        SL[col][w*16 + lg*4 + rr] = bv;
      } else {
        uBuf[(size_t)row*64 + (col-64)] = s;
      }
    }
  }
  __syncthreads();
  int col = t >> 2, q = t & 3;
  int gb = blockIdx.x >> 4, n0 = (blockIdx.x & 15)*64;
  const uint4* src = (const uint4*)&SL[col][q*16];
  uint4* dst = (uint4*)(St + (size_t)gb*65536 + (size_t)col*1024 + n0 + q*16);
  dst[0]=src[0]; dst[1]=src[1];
}

// ---------------- K4: Z = (1/(sum+1)) * ((adj(+T) @ S) + S)
// tile 32x64, BK=64, XOR-swizzled LDS, grid 1024
__global__ __launch_bounds__(256) void k4_z(const u16* __restrict__ adjbf,
    const u16* __restrict__ adjTbf, const u16* __restrict__ St,
    const float* __restrict__ colsum, const float* __restrict__ rowsum,
    u16* __restrict__ XC2){
  __shared__ u16 Al[2][32*64];   // 4KB per buf
  __shared__ u16 Bl[2][64*64];   // 8KB per buf
  int bid0 = blockIdx.x;
  int bid = (bid0 & 7)*128 + (bid0 >> 3);
  int mt = bid & 31, b = (bid>>5)&15, T = bid>>9;
  const u16* A = (T ? adjTbf : adjbf) + ((size_t)b<<20) + (size_t)mt*32*1024;
  const float* sums = (T ? rowsum : colsum) + b*1024;
  const u16* Sb = St + (size_t)b*65536;
  int t = threadIdx.x, w = t>>6, l = t&63, lr = l&15, lg = l>>4;
  int wm = w>>1, wc = w&1;
  int swz = ((l&7) ^ ((l>>3)&7)) << 4;
  const char* Ag = (const char*)A  + (size_t)(w*8  + (l>>3))*2048 + swz;
  const char* Bg = (const char*)Sb + (size_t)(w*16 + (l>>3))*2048 + swz;
  floatx4 acc[2] = {};
  gl16(Ag, (char*)Al[0] + w*1024);
  #pragma unroll
  for (int q=0;q<2;q++)
    gl16(Bg + q*16384, (char*)Bl[0] + w*2048 + q*1024);
  VMCNT0; __syncthreads();
  int cur = 0;
  for (int kk = 64; kk < 1024; kk += 64){
    gl16(Ag + kk*2, (char*)Al[cur^1] + w*1024);
    #pragma unroll
    for (int q=0;q<2;q++)
      gl16(Bg + q*16384 + kk*2, (char*)Bl[cur^1] + w*2048 + q*1024);
    #pragma unroll
    for (int kf=0; kf<2; kf++){
      int fo = (kf*64 + lg*16) ^ ((lr&7)<<4);
      bf16x8 af = *(const bf16x8*)((const char*)Al[cur] + (wm*16+lr)*128 + fo);
      #pragma unroll
      for (int nf=0; nf<2; nf++){
        bf16x8 bfr = *(const bf16x8*)((const char*)Bl[cur] + (wc*32+nf*16+lr)*128 + fo);
        acc[nf] = MFMA16(af, bfr, acc[nf]);
      }
    }
    VMCNT0; __syncthreads();
    cur ^= 1;
  }
  #pragma unroll
  for (int kf=0; kf<2; kf++){
    int fo = (kf*64 + lg*16) ^ ((lr&7)<<4);
    bf16x8 af = *(const bf16x8*)((const char*)Al[cur] + (wm*16+lr)*128 + fo);
    #pragma unroll
    for (int nf=0; nf<2; nf++){
      bf16x8 bfr = *(const bf16x8*)((const char*)Bl[cur] + (wc*32+nf*16+lr)*128 + fo);
      acc[nf] = MFMA16(af, bfr, acc[nf]);
    }
  }
  int zcol = T ? 320 : 192;
  #pragma unroll
  for (int nf = 0; nf < 2; nf++) {
    #pragma unroll
    for (int rr = 0; rr < 4; rr++) {
      int row = mt*32 + wm*16 + lg*4 + rr;
      int col = wc*32 + nf*16 + lr;
      float dinv = 1.0f / (sums[row] + 1.0f);
      size_t grow = (size_t)(b*1024 + row)*384;
      float sval = bf2f(XC2[grow + 64 + col]);
      float v2 = (acc[nf][rr] + sval) * dinv;
      XC2[grow + zcol + col] = f2bf(v2);
    }
  }
}

// ---------------- K5: candidate GEMM + tanh + GRU update -> out
__global__ __launch_bounds__(256) void k5_out(const u16* __restrict__ XC2,
    const u16* __restrict__ WcT, const float* __restrict__ bias_c,
    const float* __restrict__ uBuf, const float* __restrict__ hx,
    float* __restrict__ out){
  int w = threadIdx.x >> 6, l = threadIdx.x & 63, lr = l & 15, lg = l >> 4;
  int r0 = blockIdx.x*64 + w*16;
  floatx4 acc[4] = {};
  for (int kk = 0; kk < 384; kk += 32) {
    int ko = kk + lg*8;
    bf16x8 a = ldfrag(XC2 + (size_t)(r0 + lr)*384 + ko);
    #pragma unroll
    for (int nf = 0; nf < 4; nf++)
      acc[nf] = MFMA16(a, ldfrag(WcT + (size_t)(nf*16+lr)*384 + ko), acc[nf]);
  }
  #pragma unroll
  for (int nf = 0; nf < 4; nf++) {
    #pragma unroll
    for (int rr = 0; rr < 4; rr++) {
      int row = r0 + lg*4 + rr;
      int col = nf*16 + lr;
      float pre = acc[nf][rr] + bias_c[col];
      pre = fminf(fmaxf(pre, -15.f), 15.f);
      float e2 = __expf(2.0f*pre);
      float c = (e2 - 1.0f) / (e2 + 1.0f);
      float u = uBuf[(size_t)row*64 + col];
      float h = hx[(size_t)row*64 + col];
      out[(size_t)row*64 + col] = u*h + (1.0f - u)*c;
    }
  }
}

extern "C" void kernel_launch(void* const* d_in, const int* in_sizes, int n_in,
                              void* d_out, int out_size, void* d_ws, size_t ws_size,
                              hipStream_t stream) {
  (void)in_sizes; (void)n_in; (void)out_size; (void)ws_size;
  const float* inp = (const float*)d_in[0];
  const float* hx  = (const float*)d_in[1];
  const float* adj = (const float*)d_in[2];
  const float* W0  = (const float*)d_in[3];
  const float* b0  = (const float*)d_in[4];
  const float* W1  = (const float*)d_in[5];
  const float* b1  = (const float*)d_in[6];
  const float* Wc0 = (const float*)d_in[7];
  const float* bc0 = (const float*)d_in[8];
  const float* Wc1 = (const float*)d_in[9];
  const float* bc1 = (const float*)d_in[10];
  float* out = (float*)d_out;
  char* ws = (char*)d_ws;

  float* colsum = (float*)(ws + 0);
  float* rowsum = (float*)(ws + 65536);
  u16* adjbf  = (u16*)(ws + 131072);
  u16* adjTbf = (u16*)(ws + 33685504);
  u16* Xt     = (u16*)(ws + 67239936);
  u16* XC     = (u16*)(ws + 71434240);
  u16* XC2    = (u16*)(ws + 84017152);
  u16* St     = (u16*)(ws + 96600064);
  float* uBuf = (float*)(ws + 98697216);
  u16* WgT    = (u16*)(ws + 102891520);
  u16* WcT    = (u16*)(ws + 102989824);
  float* bias_g = (float*)(ws + 103038976);
  float* bias_c = (float*)(ws + 103039488);

  hipLaunchKernelGGL(ka_prep, dim3(544), dim3(256), 0, stream,
                     inp, hx, W0, b0, W1, b1, Wc0, bc0, Wc1, bc1,
                     WgT, WcT, bias_g, bias_c, colsum, XC, Xt, XC2);
  hipLaunchKernelGGL(k1_adj, dim3(16,16,16), dim3(256), 0, stream,
                     adj, adjbf, adjTbf, colsum, rowsum);
  hipLaunchKernelGGL(k2_y, dim3(1024), dim3(256), 0, stream,
                     adjbf, adjTbf, Xt, inp, hx, colsum, rowsum, XC, XC2);
  hipLaunchKernelGGL(k3_gates, dim3(256), dim3(256), 0, stream,
                     XC, WgT, bias_g, hx, XC2, St, uBuf);
  hipLaunchKernelGGL(k4_z, dim3(1024), dim3(256), 0, stream,
                     adjbf, adjTbf, St, colsum, rowsum, XC2);
  hipLaunchKernelGGL(k5_out, dim3(256), dim3(256), 0, stream,
                     XC2, WcT, bias_c, uBuf, hx, out);
}

// Round 6
// 85.037 us; speedup vs baseline: 1.4631x; 1.3334x over previous
//
#include <hip/hip_runtime.h>
#include <hip/hip_bf16.h>

typedef unsigned short u16;
typedef unsigned int u32;
typedef __bf16 bf16x8 __attribute__((ext_vector_type(8)));
typedef float floatx4 __attribute__((ext_vector_type(4)));

#define MFMA16(a,b,c) __builtin_amdgcn_mfma_f32_16x16x32_bf16((a),(b),(c),0,0,0)
#define AS1 __attribute__((address_space(1)))
#define AS3 __attribute__((address_space(3)))
#define VM6 asm volatile("s_waitcnt vmcnt(6)" ::: "memory")
#define VM4 asm volatile("s_waitcnt vmcnt(4)" ::: "memory")
#define VM0 asm volatile("s_waitcnt vmcnt(0)" ::: "memory")
#define SBAR __builtin_amdgcn_s_barrier()
#define SCHED0 __builtin_amdgcn_sched_barrier(0)

__device__ __forceinline__ void gl16(const void* g, void* l){
  __builtin_amdgcn_global_load_lds((const AS1 void*)g, (AS3 void*)l, 16, 0, 0);
}

__device__ __forceinline__ u16 f2bf(float f){
  u32 u = __builtin_bit_cast(u32, f);
  u += 0x7FFFu + ((u >> 16) & 1u);
  return (u16)(u >> 16);
}
__device__ __forceinline__ float bf2f(u16 h){
  u32 u = ((u32)h) << 16;
  return __builtin_bit_cast(float, u);
}
__device__ __forceinline__ bf16x8 ldfrag(const u16* p){
  return *(const bf16x8*)p;
}

// ================ KP: fused prep (X staging + weights) and adj pass =========
// blk [0,256): X staging; [256,544): weight prep; [544,4640): adj tiles
__global__ __launch_bounds__(256) void kp_prep(
    const float* __restrict__ inp, const float* __restrict__ hx,
    const float* __restrict__ adj,
    const float* __restrict__ W0, const float* __restrict__ b0,
    const float* __restrict__ W1, const float* __restrict__ b1,
    const float* __restrict__ Wc0, const float* __restrict__ bc0,
    const float* __restrict__ Wc1, const float* __restrict__ bc1,
    u16* __restrict__ WgT, u16* __restrict__ WcT,
    float* __restrict__ bias_g, float* __restrict__ bias_c,
    u16* __restrict__ adjbf, u16* __restrict__ adjTbf,
    float* __restrict__ colsum, float* __restrict__ rowsum,
    u16* __restrict__ Xt, u16* __restrict__ XC2){
  __shared__ __align__(16) u16 sh[10240];
  int t = threadIdx.x;
  int blk = blockIdx.x;
  if (blk < 256) {
    // ---- X staging: XC2 cols 0-64 (inp rows) + Xt feature-major ----
    u16 (*XT)[80] = (u16(*)[80])sh;
    int r = t >> 2;
    int row = blk*64 + r;
    int fq = t & 3;
    const float4* ip = (const float4*)(inp + (size_t)row*64 + fq*16);
    const float4* hp = (const float4*)(hx  + (size_t)row*64 + fq*16);
    float iv[16], hv[16];
    #pragma unroll
    for (int q=0;q<4;q++){
      float4 a = ip[q]; iv[4*q]=a.x; iv[4*q+1]=a.y; iv[4*q+2]=a.z; iv[4*q+3]=a.w;
      float4 c = hp[q]; hv[4*q]=c.x; hv[4*q+1]=c.y; hv[4*q+2]=c.z; hv[4*q+3]=c.w;
    }
    u16 ib[16], hb[16];
    #pragma unroll
    for (int q=0;q<16;q++){ ib[q]=f2bf(iv[q]); hb[q]=f2bf(hv[q]); }
    u32 pi[8];
    #pragma unroll
    for (int q=0;q<8;q++) pi[q] = (u32)ib[2*q] | ((u32)ib[2*q+1]<<16);
    size_t rbase = (size_t)row*384;
    *(uint4*)(XC2 + rbase + fq*16)     = make_uint4(pi[0],pi[1],pi[2],pi[3]);
    *(uint4*)(XC2 + rbase + fq*16 + 8) = make_uint4(pi[4],pi[5],pi[6],pi[7]);
    #pragma unroll
    for (int q=0;q<16;q++){
      XT[fq*16+q][r]    = ib[q];
      XT[64+fq*16+q][r] = hb[q];
    }
    __syncthreads();
    int feat = t >> 1, half = t & 1;
    int b = blk >> 4, n0 = (blk & 15)*64;
    const uint4* src = (const uint4*)&XT[feat][half*32];
    uint4* dst = (uint4*)(Xt + (size_t)b*131072 + (size_t)feat*1024 + n0 + half*32);
    dst[0]=src[0]; dst[1]=src[1]; dst[2]=src[2]; dst[3]=src[3];
    return;
  }
  if (blk < 544) {
    // ---- weight prep ----
    int id = (blk - 256)*256 + t;
    if (id < 128*384) {
      int n = id / 384, k = id % 384;
      float v;
      if (k < 128)       v = W0[(k*3+0)*128 + n] + W1[(k*3+0)*128 + n];
      else if (k < 256){ int f = k-128; v = W0[(f*3+1)*128+n] + W0[(f*3+2)*128+n]; }
      else             { int f = k-256; v = W1[(f*3+1)*128+n] + W1[(f*3+2)*128+n]; }
      WgT[(size_t)n*384 + k] = f2bf(v);
    } else {
      int id2 = id - 128*384;
      int n = id2 / 384, k = id2 % 384;
      float v;
      if (k < 128)       v = Wc0[(k*3+0)*64 + n] + Wc1[(k*3+0)*64 + n];
      else if (k < 256){ int f = k-128; v = Wc0[(f*3+1)*64+n] + Wc0[(f*3+2)*64+n]; }
      else             { int f = k-256; v = Wc1[(f*3+1)*64+n] + Wc1[(f*3+2)*64+n]; }
      WcT[(size_t)n*384 + k] = f2bf(v);
    }
    if (blk == 256) {
      if (t < 128) bias_g[t] = b0[t] + b1[t];
      if (t < 64)  bias_c[t] = bc0[t] + bc1[t];
    }
    return;
  }
  // ---- adj pass: row/col sums + bf16 copy + transposed bf16 copy ----
  u16 (*lt)[72] = (u16(*)[72])sh;
  int blk2 = blk - 544;
  int j0 = (blk2 & 15) << 6, i0 = ((blk2 >> 4) & 15) << 6, b = blk2 >> 8;
  int r = t >> 2, cq = t & 3;
  size_t base = ((size_t)b << 20);
  const float4* s4 = (const float4*)(adj + base + (size_t)(i0 + r)*1024 + j0 + (cq<<4));
  float v[16];
  #pragma unroll
  for (int q = 0; q < 4; q++) {
    float4 f = s4[q];
    v[4*q]=f.x; v[4*q+1]=f.y; v[4*q+2]=f.z; v[4*q+3]=f.w;
  }
  u32 u8[8];
  #pragma unroll
  for (int q = 0; q < 8; q++)
    u8[q] = (u32)f2bf(v[2*q]) | ((u32)f2bf(v[2*q+1]) << 16);
  uint4* d = (uint4*)(adjbf + base + (size_t)(i0 + r)*1024 + j0 + (cq<<4));
  d[0] = make_uint4(u8[0],u8[1],u8[2],u8[3]);
  d[1] = make_uint4(u8[4],u8[5],u8[6],u8[7]);
  float rs = 0.f;
  #pragma unroll
  for (int q = 0; q < 16; q++) rs += v[q];
  rs += __shfl_down(rs, 1, 64);
  rs += __shfl_down(rs, 2, 64);
  if (cq == 0) atomicAdd(&rowsum[b*1024 + i0 + r], rs);
  #pragma unroll
  for (int q = 0; q < 16; q++)
    lt[(cq<<4) + q][r] = (u16)(u8[q>>1] >> ((q&1)*16));
  __syncthreads();
  uint4 q0 = *(const uint4*)&lt[r][(cq<<4)];
  uint4 q1 = *(const uint4*)&lt[r][(cq<<4) + 8];
  uint4* dT = (uint4*)(adjTbf + base + (size_t)(j0 + r)*1024 + i0 + (cq<<4));
  dT[0] = q0; dT[1] = q1;
  u32 w8[8] = {q0.x,q0.y,q0.z,q0.w,q1.x,q1.y,q1.z,q1.w};
  float cs = 0.f;
  #pragma unroll
  for (int q = 0; q < 8; q++)
    cs += bf2f((u16)(w8[q] & 0xFFFFu)) + bf2f((u16)(w8[q] >> 16));
  cs += __shfl_down(cs, 1, 64);
  cs += __shfl_down(cs, 2, 64);
  if (cq == 0) atomicAdd(&colsum[b*1024 + j0 + r], cs);
}

// ================ KG: both-direction diffusion + gates, fused ===============
// grid 512: 32-row tile; per block: Y0,Y1 (16 MFMA/step/wave) -> SL -> gates
__global__ __launch_bounds__(256) void kg_gates(
    const u16* __restrict__ adjbf, const u16* __restrict__ adjTbf,
    const u16* __restrict__ Xt,
    const float* __restrict__ inp, const float* __restrict__ hx,
    const float* __restrict__ colsum, const float* __restrict__ rowsum,
    const u16* __restrict__ WgT, const float* __restrict__ bias_g,
    u16* __restrict__ XC2, u16* __restrict__ St, float* __restrict__ uBuf){
  __shared__ __align__(16) u16 lds[24576];   // 48 KB
  char* ldsb = (char*)lds;
  int bid0 = blockIdx.x;
  int bid = (bid0 & 7)*64 + (bid0 >> 3);     // XCD swizzle, 512 = 8*64
  int mt = bid & 31, b = bid >> 5;
  const u16* A0 = adjbf  + ((size_t)b<<20) + (size_t)mt*32*1024;
  const u16* A1 = adjTbf + ((size_t)b<<20) + (size_t)mt*32*1024;
  const u16* Xb = Xt + (size_t)b*131072;
  int t = threadIdx.x, w = t>>6, l = t&63, lr = l&15, lg = l>>4;
  int wm = w>>1, wn = w&1;
  int swz = ((l&7) ^ ((l>>3)&7)) << 4;
  const char* A0g = (const char*)A0 + (size_t)(w*8  + (l>>3))*2048 + swz;
  const char* A1g = (const char*)A1 + (size_t)(w*8  + (l>>3))*2048 + swz;
  const char* Bg  = (const char*)Xb + (size_t)(w*32 + (l>>3))*2048 + swz;
  floatx4 acc0[4] = {}, acc1[4] = {};
  // lds bytes: A0[buf]: buf*4096 ; A1[buf]: 8192+buf*4096 ; B[buf]: 16384+buf*16384
  #define STAGE_KG(bufi, kk) do{ \
    gl16(A0g + (size_t)(kk)*2, ldsb + (bufi)*4096 + w*1024); \
    gl16(A1g + (size_t)(kk)*2, ldsb + 8192 + (bufi)*4096 + w*1024); \
    gl16(Bg + 0*16384 + (size_t)(kk)*2, ldsb + 16384 + (bufi)*16384 + w*4096 + 0*1024); \
    gl16(Bg + 1*16384 + (size_t)(kk)*2, ldsb + 16384 + (bufi)*16384 + w*4096 + 1*1024); \
    gl16(Bg + 2*16384 + (size_t)(kk)*2, ldsb + 16384 + (bufi)*16384 + w*4096 + 2*1024); \
    gl16(Bg + 3*16384 + (size_t)(kk)*2, ldsb + 16384 + (bufi)*16384 + w*4096 + 3*1024); \
  }while(0)
  STAGE_KG(0, 0);
  for (int step = 0; step < 16; ++step){
    int cur = step & 1;
    if (step < 15) { STAGE_KG(cur^1, (step+1)*64); VM6; } else { VM0; }
    SBAR; SCHED0;
    #pragma unroll
    for (int kf=0; kf<2; kf++){
      int fo = (kf*64 + lg*16) ^ ((lr&7)<<4);
      bf16x8 a0 = *(const bf16x8*)(ldsb + cur*4096 + (wm*16+lr)*128 + fo);
      bf16x8 a1 = *(const bf16x8*)(ldsb + 8192 + cur*4096 + (wm*16+lr)*128 + fo);
      #pragma unroll
      for (int nf=0; nf<4; nf++){
        bf16x8 bb = *(const bf16x8*)(ldsb + 16384 + cur*16384 + (wn*64+nf*16+lr)*128 + fo);
        acc0[nf] = MFMA16(a0, bb, acc0[nf]);
        acc1[nf] = MFMA16(a1, bb, acc1[nf]);
      }
    }
    SCHED0; SBAR;
  }
  __syncthreads();
  // ---- epilogue: build SL[32][392] = [x(128) | Y0(128) | Y1(128)] ----
  u16* SL = lds;                 // row stride 392 u16
  u16* SLT = lds + 12544;        // [64][40] for St transpose
  float d0i[4], d1i[4];
  #pragma unroll
  for (int rr=0; rr<4; rr++){
    int row = mt*32 + wm*16 + lg*4 + rr;
    d0i[rr] = 1.0f / (colsum[b*1024 + row] + 1.0f);
    d1i[rr] = 1.0f / (rowsum[b*1024 + row] + 1.0f);
  }
  #pragma unroll
  for (int nf = 0; nf < 4; nf++) {
    #pragma unroll
    for (int rr = 0; rr < 4; rr++) {
      int rl = wm*16 + lg*4 + rr;
      int row = mt*32 + rl;
      int col = wn*64 + nf*16 + lr;
      float xv = (col < 64) ? inp[(size_t)(b*1024+row)*64 + col]
                            : hx [(size_t)(b*1024+row)*64 + (col-64)];
      float y0 = (acc0[nf][rr] + xv) * d0i[rr];
      float y1 = (acc1[nf][rr] + xv) * d1i[rr];
      u16 b0v = f2bf(y0), b1v = f2bf(y1);
      SL[rl*392 + col]       = f2bf(xv);
      SL[rl*392 + 128 + col] = b0v;
      SL[rl*392 + 256 + col] = b1v;
      if (col < 64) {
        size_t grow = (size_t)(b*1024 + row)*384;
        XC2[grow + 128 + col] = b0v;
        XC2[grow + 256 + col] = b1v;
      }
    }
  }
  __syncthreads();
  // ---- gates GEMM: 32x384 @ 384x128 ----
  floatx4 g[4] = {};
  for (int kk = 0; kk < 384; kk += 32) {
    int ko = kk + lg*8;
    bf16x8 a = ldfrag(&SL[(size_t)(wm*16+lr)*392 + ko]);
    #pragma unroll
    for (int nf = 0; nf < 4; nf++)
      g[nf] = MFMA16(a, ldfrag(WgT + (size_t)(wn*64+nf*16+lr)*384 + ko), g[nf]);
  }
  #pragma unroll
  for (int nf = 0; nf < 4; nf++) {
    #pragma unroll
    for (int rr = 0; rr < 4; rr++) {
      int rl = wm*16 + lg*4 + rr;
      int row = mt*32 + rl;
      int col = wn*64 + nf*16 + lr;
      float pre = g[nf][rr] + bias_g[col];
      float s = 1.0f / (1.0f + __expf(-pre));
      if (col < 64) {          // r gate
        float sh = s * hx[(size_t)(b*1024+row)*64 + col];
        u16 bv = f2bf(sh);
        XC2[(size_t)(b*1024+row)*384 + 64 + col] = bv;
        SLT[col*40 + rl] = bv;
      } else {                 // u gate
        uBuf[(size_t)(b*1024+row)*64 + (col-64)] = s;
      }
    }
  }
  __syncthreads();
  // St writeout (feature-major), coalesced
  {
    int c2 = t >> 2, q = t & 3;
    uint4 vv = *(const uint4*)&SLT[c2*40 + q*8];
    *(uint4*)(St + (size_t)b*65536 + (size_t)c2*1024 + mt*32 + q*8) = vv;
  }
  #undef STAGE_KG
}

// ================ KZ: both-direction Z diffusion + candidate + GRU ==========
__global__ __launch_bounds__(256) void kz_cand(
    const u16* __restrict__ adjbf, const u16* __restrict__ adjTbf,
    const u16* __restrict__ St,
    const float* __restrict__ colsum, const float* __restrict__ rowsum,
    const u16* __restrict__ XC2, const u16* __restrict__ WcT,
    const float* __restrict__ bias_c,
    const float* __restrict__ uBuf, const float* __restrict__ hx,
    float* __restrict__ out){
  __shared__ __align__(16) u16 lds[16384];   // 32 KB
  char* ldsb = (char*)lds;
  int bid0 = blockIdx.x;
  int bid = (bid0 & 7)*64 + (bid0 >> 3);
  int mt = bid & 31, b = bid >> 5;
  const u16* A0 = adjbf  + ((size_t)b<<20) + (size_t)mt*32*1024;
  const u16* A1 = adjTbf + ((size_t)b<<20) + (size_t)mt*32*1024;
  const u16* Sb = St + (size_t)b*65536;
  int t = threadIdx.x, w = t>>6, l = t&63, lr = l&15, lg = l>>4;
  int wm = w>>1, wn = w&1;
  int swz = ((l&7) ^ ((l>>3)&7)) << 4;
  const char* A0g = (const char*)A0 + (size_t)(w*8  + (l>>3))*2048 + swz;
  const char* A1g = (const char*)A1 + (size_t)(w*8  + (l>>3))*2048 + swz;
  const char* Bg  = (const char*)Sb + (size_t)(w*16 + (l>>3))*2048 + swz;
  floatx4 z0[2] = {}, z1[2] = {};
  // lds bytes: A0[buf]: buf*4096 ; A1[buf]: 8192+buf*4096 ; B[buf]: 16384+buf*8192
  #define STAGE_KZ(bufi, kk) do{ \
    gl16(A0g + (size_t)(kk)*2, ldsb + (bufi)*4096 + w*1024); \
    gl16(A1g + (size_t)(kk)*2, ldsb + 8192 + (bufi)*4096 + w*1024); \
    gl16(Bg + 0*16384 + (size_t)(kk)*2, ldsb + 16384 + (bufi)*8192 + w*2048 + 0*1024); \
    gl16(Bg + 1*16384 + (size_t)(kk)*2, ldsb + 16384 + (bufi)*8192 + w*2048 + 1*1024); \
  }while(0)
  STAGE_KZ(0, 0);
  for (int step = 0; step < 16; ++step){
    int cur = step & 1;
    if (step < 15) { STAGE_KZ(cur^1, (step+1)*64); VM4; } else { VM0; }
    SBAR; SCHED0;
    #pragma unroll
    for (int kf=0; kf<2; kf++){
      int fo = (kf*64 + lg*16) ^ ((lr&7)<<4);
      bf16x8 a0 = *(const bf16x8*)(ldsb + cur*4096 + (wm*16+lr)*128 + fo);
      bf16x8 a1 = *(const bf16x8*)(ldsb + 8192 + cur*4096 + (wm*16+lr)*128 + fo);
      #pragma unroll
      for (int nf=0; nf<2; nf++){
        bf16x8 bb = *(const bf16x8*)(ldsb + 16384 + cur*8192 + (wn*32+nf*16+lr)*128 + fo);
        z0[nf] = MFMA16(a0, bb, z0[nf]);
        z1[nf] = MFMA16(a1, bb, z1[nf]);
      }
    }
    SCHED0; SBAR;
  }
  __syncthreads();
  // ---- SL[32][392] = [x|S (0:128) | Y0inp|Z0 (128:256) | Y1inp|Z1 (256:384)]
  u16* SL = lds;
  {
    int rl = t >> 3, s = t & 7;
    size_t grow = (size_t)(b*1024 + mt*32 + rl)*384;
    #pragma unroll
    for (int j = 0; j < 3; j++)
      *(uint4*)&SL[(size_t)rl*392 + s*24 + j*8] =
        *(const uint4*)(XC2 + grow + s*24 + j*8);
    *(uint4*)&SL[(size_t)rl*392 + 256 + s*8] =
      *(const uint4*)(XC2 + grow + 256 + s*8);
  }
  float d0i[4], d1i[4];
  #pragma unroll
  for (int rr=0; rr<4; rr++){
    int row = mt*32 + wm*16 + lg*4 + rr;
    d0i[rr] = 1.0f / (colsum[b*1024 + row] + 1.0f);
    d1i[rr] = 1.0f / (rowsum[b*1024 + row] + 1.0f);
  }
  #pragma unroll
  for (int nf = 0; nf < 2; nf++) {
    #pragma unroll
    for (int rr = 0; rr < 4; rr++) {
      int rl = wm*16 + lg*4 + rr;
      int row = mt*32 + rl;
      int col = wn*32 + nf*16 + lr;     // 0..63
      float sval = bf2f(XC2[(size_t)(b*1024+row)*384 + 64 + col]);
      SL[rl*392 + 192 + col] = f2bf((z0[nf][rr] + sval) * d0i[rr]);
      SL[rl*392 + 320 + col] = f2bf((z1[nf][rr] + sval) * d1i[rr]);
    }
  }
  __syncthreads();
  // ---- candidate GEMM 32x384 @ 384x64 + tanh + GRU ----
  floatx4 c[2] = {};
  for (int kk = 0; kk < 384; kk += 32) {
    int ko = kk + lg*8;
    bf16x8 a = ldfrag(&SL[(size_t)(wm*16+lr)*392 + ko]);
    #pragma unroll
    for (int nf = 0; nf < 2; nf++)
      c[nf] = MFMA16(a, ldfrag(WcT + (size_t)(wn*32+nf*16+lr)*384 + ko), c[nf]);
  }
  #pragma unroll
  for (int nf = 0; nf < 2; nf++) {
    #pragma unroll
    for (int rr = 0; rr < 4; rr++) {
      int row = mt*32 + wm*16 + lg*4 + rr;
      int col = wn*32 + nf*16 + lr;
      float pre = c[nf][rr] + bias_c[col];
      pre = fminf(fmaxf(pre, -15.f), 15.f);
      float e2 = __expf(2.0f*pre);
      float cv = (e2 - 1.0f) / (e2 + 1.0f);
      float u = uBuf[(size_t)(b*1024+row)*64 + col];
      float h = hx[(size_t)(b*1024+row)*64 + col];
      out[(size_t)(b*1024+row)*64 + col] = u*h + (1.0f - u)*cv;
    }
  }
  #undef STAGE_KZ
}

extern "C" void kernel_launch(void* const* d_in, const int* in_sizes, int n_in,
                              void* d_out, int out_size, void* d_ws, size_t ws_size,
                              hipStream_t stream) {
  (void)in_sizes; (void)n_in; (void)out_size; (void)ws_size;
  const float* inp = (const float*)d_in[0];
  const float* hx  = (const float*)d_in[1];
  const float* adj = (const float*)d_in[2];
  const float* W0  = (const float*)d_in[3];
  const float* b0  = (const float*)d_in[4];
  const float* W1  = (const float*)d_in[5];
  const float* b1  = (const float*)d_in[6];
  const float* Wc0 = (const float*)d_in[7];
  const float* bc0 = (const float*)d_in[8];
  const float* Wc1 = (const float*)d_in[9];
  const float* bc1 = (const float*)d_in[10];
  float* out = (float*)d_out;
  char* ws = (char*)d_ws;

  float* colsum = (float*)(ws + 0);
  float* rowsum = (float*)(ws + 65536);
  u16* adjbf  = (u16*)(ws + 131072);
  u16* adjTbf = (u16*)(ws + 33685504);
  u16* Xt     = (u16*)(ws + 67239936);
  u16* XC2    = (u16*)(ws + 84017152);
  u16* St     = (u16*)(ws + 96600064);
  float* uBuf = (float*)(ws + 98697216);
  u16* WgT    = (u16*)(ws + 102891520);
  u16* WcT    = (u16*)(ws + 102989824);
  float* bias_g = (float*)(ws + 103038976);
  float* bias_c = (float*)(ws + 103039488);

  hipMemsetAsync(colsum, 0, 131072, stream);
  hipLaunchKernelGGL(kp_prep, dim3(4640), dim3(256), 0, stream,
                     inp, hx, adj, W0, b0, W1, b1, Wc0, bc0, Wc1, bc1,
                     WgT, WcT, bias_g, bias_c, adjbf, adjTbf, colsum, rowsum,
                     Xt, XC2);
  hipLaunchKernelGGL(kg_gates, dim3(512), dim3(256), 0, stream,
                     adjbf, adjTbf, Xt, inp, hx, colsum, rowsum,
                     WgT, bias_g, XC2, St, uBuf);
  hipLaunchKernelGGL(kz_cand, dim3(512), dim3(256), 0, stream,
                     adjbf, adjTbf, St, colsum, rowsum,
                     XC2, WcT, bias_c, uBuf, hx, out);
}